// Round 2
// baseline (716.007 us; speedup 1.0000x reference)
//
#include <hip/hip_runtime.h>

#define EMB 16
typedef unsigned long long u64;

// ---------------- common small kernels ----------------

__global__ void zero_f32(float* __restrict__ p, size_t n) {
    size_t i = (size_t)blockIdx.x * blockDim.x + threadIdx.x;
    size_t stride = (size_t)gridDim.x * blockDim.x;
    for (; i < n; i += stride) p[i] = 0.0f;
}

__global__ void zero_i32(int* __restrict__ p, int n) {
    int i = blockIdx.x * blockDim.x + threadIdx.x;
    if (i < n) p[i] = 0;
}

// Y[row,j] = X[row,:] @ W[:,j] + (b ? b[j] : 0).  One thread per (row, j).
__global__ void linear16_kernel(const float* __restrict__ X, const float* __restrict__ W,
                                const float* __restrict__ b, float* __restrict__ Y, int N) {
    int tid = blockIdx.x * blockDim.x + threadIdx.x;
    int row = tid >> 4;
    int j = tid & 15;
    if (row >= N) return;
    float acc = b ? b[j] : 0.0f;
    const float* xr = X + (size_t)row * EMB;
#pragma unroll
    for (int k = 0; k < EMB; ++k) acc = fmaf(xr[k], W[k * EMB + j], acc);
    Y[(size_t)row * EMB + j] = acc;
}

// ---------------- CSR build ----------------

__global__ void degree_kernel(const int* __restrict__ ridx, int* __restrict__ deg, int E) {
    int e = blockIdx.x * blockDim.x + threadIdx.x;
    if (e < E) atomicAdd(&deg[ridx[e]], 1);
}

// single-block exclusive scan over deg[0..N) -> off[], cursor[]
__global__ void scan_kernel(const int* __restrict__ deg, int* __restrict__ off,
                            int* __restrict__ cursor, int N) {
    __shared__ int part[1024];
    int t = threadIdx.x;
    int chunk = (N + 1023) >> 10;
    int lo = t * chunk;
    int hi = lo + chunk; if (hi > N) hi = N; if (lo > N) lo = N;
    int s = 0;
    for (int i = lo; i < hi; ++i) s += deg[i];
    part[t] = s;
    __syncthreads();
    for (int d = 1; d < 1024; d <<= 1) {
        int v = (t >= d) ? part[t - d] : 0;
        __syncthreads();
        part[t] += v;
        __syncthreads();
    }
    int base = part[t] - s;  // exclusive prefix of this chunk
    for (int i = lo; i < hi; ++i) {
        off[i] = base;
        cursor[i] = base;
        base += deg[i];
    }
}

// rec[pos] = pack(left_idx, edge_feature)
__global__ void reorder_kernel(const int* __restrict__ eidx, const float* __restrict__ ef,
                               int* __restrict__ cursor, u64* __restrict__ rec, int E) {
    int e = blockIdx.x * blockDim.x + threadIdx.x;
    if (e >= E) return;
    int l = eidx[e];
    int r = eidx[E + e];
    float f = ef[e];
    int pos = atomicAdd(&cursor[r], 1);
    rec[pos] = ((u64)__float_as_uint(f) << 32) | (unsigned)l;
}

// ---------------- gather: one wave per right node ----------------
// S[r,j] = sum_e relu(L[l_e,j] + f_e*We[j] + R[r,j])
__launch_bounds__(256)
__global__ void gather_kernel(const u64* __restrict__ rec, const int* __restrict__ off,
                              const int* __restrict__ deg,
                              const float* __restrict__ L, const float* __restrict__ R,
                              const float* __restrict__ We, float* __restrict__ S, int N) {
    int wid = (blockIdx.x * blockDim.x + threadIdx.x) >> 6;
    int lane = threadIdx.x & 63;
    int sub = lane >> 4;
    int j = lane & 15;
    if (wid >= N) return;
    int start = off[wid];
    int d = deg[wid];
    float wej = We[j];
    float rj = R[(size_t)wid * EMB + j];
    float acc = 0.0f;
    for (int i = sub; i < d; i += 4) {
        u64 rc = rec[start + i];
        int l = (int)(unsigned)(rc & 0xffffffffu);
        float f = __uint_as_float((unsigned)(rc >> 32));
        float v = fmaf(f, wej, L[(size_t)l * EMB + j]) + rj;
        acc += fmaxf(v, 0.0f);
    }
    acc += __shfl_xor(acc, 16, 64);
    acc += __shfl_xor(acc, 32, 64);
    if (lane < 16) S[(size_t)wid * EMB + j] = acc;
}

// ---------------- fallback atomic edge kernel (small ws) ----------------

__global__ void edge_kernel(const int* __restrict__ eidx, const float* __restrict__ ef,
                            const float* __restrict__ L, const float* __restrict__ R,
                            const float* __restrict__ We, float* __restrict__ S,
                            int* __restrict__ cnt, int E) {
    long long tid = (long long)blockIdx.x * blockDim.x + threadIdx.x;
    int e = (int)(tid >> 4);
    int j = (int)(tid & 15);
    if (e >= E) return;
    int l = eidx[e];
    int r = eidx[E + e];
    float v = L[(size_t)l * EMB + j] + ef[e] * We[j] + R[(size_t)r * EMB + j];
    v = fmaxf(v, 0.0f);
    atomicAdd(&S[(size_t)r * EMB + j], v);
    if (j == 0) atomicAdd(&cnt[r], 1);
}

// ---------------- per-node epilogue ----------------
// agg = S@Wf + deg*bf ; post = relu(agg)@Wp + bp ; h=[post, rf] ;
// out = relu(h@Wo1 + bo1)@Wo2 + bo2.  One thread per node.
__global__ void final_kernel(const float* __restrict__ S, const int* __restrict__ deg,
                             const float* __restrict__ rf,
                             const float* __restrict__ Wf, const float* __restrict__ bf,
                             const float* __restrict__ Wp, const float* __restrict__ bp,
                             const float* __restrict__ Wo1, const float* __restrict__ bo1,
                             const float* __restrict__ Wo2, const float* __restrict__ bo2,
                             float* __restrict__ out, int N) {
    __shared__ float sWf[256], sWp[256], sWo1[512], sWo2[256];
    __shared__ float sb[64];  // [bf | bp | bo1 | bo2]
    int t = threadIdx.x;
    for (int i = t; i < 256; i += 256) { sWf[i] = Wf[i]; sWp[i] = Wp[i]; sWo2[i] = Wo2[i]; }
    for (int i = t; i < 512; i += 256) sWo1[i] = Wo1[i];
    if (t < 16) { sb[t] = bf[t]; sb[16 + t] = bp[t]; sb[32 + t] = bo1[t]; sb[48 + t] = bo2[t]; }
    __syncthreads();

    int r = blockIdx.x * blockDim.x + t;
    if (r >= N) return;

    float s[16], x[16], y[16], rv[16], z[16], o[16];
    const float4* Sp = (const float4*)(S + (size_t)r * EMB);
    const float4* Rp = (const float4*)(rf + (size_t)r * EMB);
#pragma unroll
    for (int k = 0; k < 4; ++k) {
        float4 v = Sp[k];
        s[4 * k] = v.x; s[4 * k + 1] = v.y; s[4 * k + 2] = v.z; s[4 * k + 3] = v.w;
        float4 w = Rp[k];
        rv[4 * k] = w.x; rv[4 * k + 1] = w.y; rv[4 * k + 2] = w.z; rv[4 * k + 3] = w.w;
    }
    float c = (float)deg[r];

#pragma unroll
    for (int j = 0; j < 16; ++j) {
        float a = c * sb[j];
#pragma unroll
        for (int k = 0; k < 16; ++k) a = fmaf(s[k], sWf[k * 16 + j], a);
        x[j] = fmaxf(a, 0.0f);
    }
#pragma unroll
    for (int j = 0; j < 16; ++j) {
        float a = sb[16 + j];
#pragma unroll
        for (int k = 0; k < 16; ++k) a = fmaf(x[k], sWp[k * 16 + j], a);
        y[j] = a;
    }
#pragma unroll
    for (int j = 0; j < 16; ++j) {
        float a = sb[32 + j];
#pragma unroll
        for (int k = 0; k < 16; ++k) a = fmaf(y[k], sWo1[k * 16 + j], a);
#pragma unroll
        for (int k = 0; k < 16; ++k) a = fmaf(rv[k], sWo1[(16 + k) * 16 + j], a);
        z[j] = fmaxf(a, 0.0f);
    }
#pragma unroll
    for (int j = 0; j < 16; ++j) {
        float a = sb[48 + j];
#pragma unroll
        for (int k = 0; k < 16; ++k) a = fmaf(z[k], sWo2[k * 16 + j], a);
        o[j] = a;
    }
    float4* Op = (float4*)(out + (size_t)r * EMB);
#pragma unroll
    for (int k = 0; k < 4; ++k)
        Op[k] = make_float4(o[4 * k], o[4 * k + 1], o[4 * k + 2], o[4 * k + 3]);
}

extern "C" void kernel_launch(void* const* d_in, const int* in_sizes, int n_in,
                              void* d_out, int out_size, void* d_ws, size_t ws_size,
                              hipStream_t stream) {
    const float* lf     = (const float*)d_in[0];
    const int*   eidx   = (const int*)d_in[1];
    const float* ef     = (const float*)d_in[2];
    const float* rf     = (const float*)d_in[3];
    const float* W_left = (const float*)d_in[4];
    const float* b_left = (const float*)d_in[5];
    const float* W_edge = (const float*)d_in[6];
    const float* W_right= (const float*)d_in[7];
    const float* W_final= (const float*)d_in[8];
    const float* b_final= (const float*)d_in[9];
    const float* W_post = (const float*)d_in[10];
    const float* b_post = (const float*)d_in[11];
    const float* W_out1 = (const float*)d_in[12];
    const float* b_out1 = (const float*)d_in[13];
    const float* W_out2 = (const float*)d_in[14];
    const float* b_out2 = (const float*)d_in[15];

    int n_left  = in_sizes[0] / EMB;
    int E       = in_sizes[2];
    int n_right = in_sizes[3] / EMB;
    float* out = (float*)d_out;

    size_t need = (size_t)E * 8                                   // rec
                + ((size_t)n_left + 2 * (size_t)n_right) * EMB * 4 // L, R, S
                + (size_t)n_right * 3 * 4;                         // deg, off, cursor

    if (ws_size >= need) {
        // ---------- CSR-gather path (no atomics in the hot loop) ----------
        u64*   rec    = (u64*)d_ws;
        float* L      = (float*)(rec + (size_t)E);
        float* R      = L + (size_t)n_left * EMB;
        float* S      = R + (size_t)n_right * EMB;
        int*   deg    = (int*)(S + (size_t)n_right * EMB);
        int*   off    = deg + n_right;
        int*   cursor = off + n_right;

        zero_i32<<<(n_right + 255) / 256, 256, 0, stream>>>(deg, n_right);
        linear16_kernel<<<(n_left * EMB + 255) / 256, 256, 0, stream>>>(lf, W_left, b_left, L, n_left);
        linear16_kernel<<<(n_right * EMB + 255) / 256, 256, 0, stream>>>(rf, W_right, nullptr, R, n_right);

        degree_kernel<<<(E + 255) / 256, 256, 0, stream>>>(eidx + E, deg, E);
        scan_kernel<<<1, 1024, 0, stream>>>(deg, off, cursor, n_right);
        reorder_kernel<<<(E + 255) / 256, 256, 0, stream>>>(eidx, ef, cursor, rec, E);

        gather_kernel<<<(n_right * 64 + 255) / 256, 256, 0, stream>>>(rec, off, deg, L, R, W_edge, S, n_right);

        final_kernel<<<(n_right + 255) / 256, 256, 0, stream>>>(S, deg, rf,
            W_final, b_final, W_post, b_post, W_out1, b_out1, W_out2, b_out2, out, n_right);
    } else {
        // ---------- fallback: atomic scatter path ----------
        float* L   = (float*)d_ws;
        float* R   = L + (size_t)n_left * EMB;
        float* S   = R + (size_t)n_right * EMB;
        int*   cnt = (int*)(S + (size_t)n_right * EMB);

        zero_f32<<<2048, 256, 0, stream>>>(S, (size_t)n_right * EMB);
        zero_i32<<<(n_right + 255) / 256, 256, 0, stream>>>(cnt, n_right);

        linear16_kernel<<<(n_left * EMB + 255) / 256, 256, 0, stream>>>(lf, W_left, b_left, L, n_left);
        linear16_kernel<<<(n_right * EMB + 255) / 256, 256, 0, stream>>>(rf, W_right, nullptr, R, n_right);

        long long ethreads = (long long)E * EMB;
        edge_kernel<<<(unsigned)((ethreads + 255) / 256), 256, 0, stream>>>(eidx, ef, L, R, W_edge, S, cnt, E);

        final_kernel<<<(n_right + 255) / 256, 256, 0, stream>>>(S, cnt, rf,
            W_final, b_final, W_post, b_post, W_out1, b_out1, W_out2, b_out2, out, n_right);
    }
}

// Round 3
// 521.731 us; speedup vs baseline: 1.3724x; 1.3724x over previous
//
#include <hip/hip_runtime.h>

#define EMB 16
#define NRB 256      // right-nodes per bucket (bucket = r >> 8)
#define MAXNB 512    // max buckets supported by LDS arrays
#define CHUNK 2048   // edges per partition block
typedef unsigned long long u64;

// ---------------- tiny utility kernels ----------------

__global__ void zero_f32(float* __restrict__ p, size_t n) {
    size_t i = (size_t)blockIdx.x * blockDim.x + threadIdx.x;
    size_t stride = (size_t)gridDim.x * blockDim.x;
    for (; i < n; i += stride) p[i] = 0.0f;
}

__global__ void zero_i32(int* __restrict__ p, int n) {
    int i = blockIdx.x * blockDim.x + threadIdx.x;
    if (i < n) p[i] = 0;
}

// Y[row,j] = X[row,:] @ W[:,j] + (b ? b[j] : 0).  One thread per (row, j).
__global__ void linear16_kernel(const float* __restrict__ X, const float* __restrict__ W,
                                const float* __restrict__ b, float* __restrict__ Y, int N) {
    int tid = blockIdx.x * blockDim.x + threadIdx.x;
    int row = tid >> 4;
    int j = tid & 15;
    if (row >= N) return;
    float acc = b ? b[j] : 0.0f;
    const float* xr = X + (size_t)row * EMB;
#pragma unroll
    for (int k = 0; k < EMB; ++k) acc = fmaf(xr[k], W[k * EMB + j], acc);
    Y[(size_t)row * EMB + j] = acc;
}

// ---------------- bucket CSR build ----------------

__global__ void bucket_hist_kernel(const int* __restrict__ ridx, int* __restrict__ bhist,
                                   int E, int NB) {
    __shared__ int h[MAXNB];
    int t = threadIdx.x;
    for (int i = t; i < NB; i += 256) h[i] = 0;
    __syncthreads();
    int idx = blockIdx.x * blockDim.x + t;
    int stride = gridDim.x * blockDim.x;
    for (int e = idx; e < E; e += stride) atomicAdd(&h[ridx[e] >> 8], 1);
    __syncthreads();
    for (int i = t; i < NB; i += 256) if (h[i]) atomicAdd(&bhist[i], h[i]);
}

// single block of 512 threads; NB < 512
__global__ void bucket_scan_kernel(const int* __restrict__ bhist, int* __restrict__ boff,
                                   int* __restrict__ gcur, int NB) {
    __shared__ int sc[512];
    int t = threadIdx.x;
    int v = (t < NB) ? bhist[t] : 0;
    sc[t] = v;
    __syncthreads();
    for (int d = 1; d < 512; d <<= 1) {
        int x = (t >= d) ? sc[t - d] : 0;
        __syncthreads();
        sc[t] += x;
        __syncthreads();
    }
    int excl = sc[t] - v;  // exclusive prefix
    if (t <= NB) boff[t] = excl;  // t == NB gives total == E
    if (t < NB) gcur[t] = excl;
}

// rec = [f:32][l:24][r_local:8]
__launch_bounds__(256)
__global__ void partition_kernel(const int* __restrict__ eidx, const float* __restrict__ ef,
                                 int* __restrict__ gcur, u64* __restrict__ rec,
                                 int E, int NB) {
    __shared__ u64 srec[CHUNK];
    __shared__ unsigned short sbkt[CHUNK];
    __shared__ int hist[MAXNB];
    __shared__ int lbase[MAXNB];
    int t = threadIdx.x;
    int base = blockIdx.x * CHUNK;
    int n = E - base; if (n > CHUNK) n = CHUNK;
    for (int i = t; i < NB; i += 256) hist[i] = 0;
    __syncthreads();
    for (int i = t; i < n; i += 256) {
        int e = base + i;
        int l = eidx[e];
        int r = eidx[E + e];
        float f = ef[e];
        int b = r >> 8;
        srec[i] = ((u64)__float_as_uint(f) << 32) | ((u64)(unsigned)l << 8) | (unsigned)(r & 255);
        sbkt[i] = (unsigned short)b;
        atomicAdd(&hist[b], 1);
    }
    __syncthreads();
    for (int i = t; i < NB; i += 256) {
        int h = hist[i];
        lbase[i] = h ? atomicAdd(&gcur[i], h) : 0;
        hist[i] = 0;  // reuse as local cursor
    }
    __syncthreads();
    for (int i = t; i < n; i += 256) {
        int b = sbkt[i];
        int pos = lbase[b] + atomicAdd(&hist[b], 1);
        rec[pos] = srec[i];
    }
}

// ---------------- phase 2: one block per bucket, LDS accumulation ----------------
// S[r,j] = sum_e relu(L[l_e,j] + f_e*We[j] + R[r,j]);  deg[r] = count
__launch_bounds__(1024)
__global__ void bucket_gather_kernel(const u64* __restrict__ rec, const int* __restrict__ boff,
                                     const float* __restrict__ L, const float* __restrict__ R,
                                     const float* __restrict__ We,
                                     float* __restrict__ S, int* __restrict__ deg, int n_right) {
    __shared__ float Stile[NRB * EMB];   // 16 KB
    __shared__ float Rtile[NRB * EMB];   // 16 KB
    __shared__ int dtile[NRB];           // 1 KB
    int b = blockIdx.x;
    int t = threadIdx.x;
    int node0 = b << 8;
    int nn = n_right - node0; if (nn > NRB) nn = NRB;

    for (int i = t; i < NRB * EMB; i += 1024) Stile[i] = 0.0f;
    for (int i = t; i < nn * EMB; i += 1024) Rtile[i] = R[(size_t)node0 * EMB + i];
    for (int i = t; i < NRB; i += 1024) dtile[i] = 0;
    __syncthreads();

    int start = boff[b], end = boff[b + 1];
    int j = t & 15;
    int sub = t >> 4;  // 0..63 record slots
    float wej = We[j];
    for (int i = start + sub; i < end; i += 64) {
        u64 rc = rec[i];
        int rl = (int)(rc & 255u);
        int l = (int)((rc >> 8) & 0xffffffu);
        float f = __uint_as_float((unsigned)(rc >> 32));
        float v = fmaf(f, wej, L[(size_t)l * EMB + j]) + Rtile[rl * EMB + j];
        v = fmaxf(v, 0.0f);
        atomicAdd(&Stile[rl * EMB + j], v);
        if (j == 0) atomicAdd(&dtile[rl], 1);
    }
    __syncthreads();
    for (int i = t; i < nn * EMB; i += 1024) S[(size_t)node0 * EMB + i] = Stile[i];
    for (int i = t; i < nn; i += 1024) deg[node0 + i] = dtile[i];
}

// ---------------- fallback atomic edge kernel (small ws) ----------------

__global__ void edge_kernel(const int* __restrict__ eidx, const float* __restrict__ ef,
                            const float* __restrict__ L, const float* __restrict__ R,
                            const float* __restrict__ We, float* __restrict__ S,
                            int* __restrict__ cnt, int E) {
    long long tid = (long long)blockIdx.x * blockDim.x + threadIdx.x;
    int e = (int)(tid >> 4);
    int j = (int)(tid & 15);
    if (e >= E) return;
    int l = eidx[e];
    int r = eidx[E + e];
    float v = L[(size_t)l * EMB + j] + ef[e] * We[j] + R[(size_t)r * EMB + j];
    v = fmaxf(v, 0.0f);
    atomicAdd(&S[(size_t)r * EMB + j], v);
    if (j == 0) atomicAdd(&cnt[r], 1);
}

// ---------------- per-node epilogue ----------------
__global__ void final_kernel(const float* __restrict__ S, const int* __restrict__ deg,
                             const float* __restrict__ rf,
                             const float* __restrict__ Wf, const float* __restrict__ bf,
                             const float* __restrict__ Wp, const float* __restrict__ bp,
                             const float* __restrict__ Wo1, const float* __restrict__ bo1,
                             const float* __restrict__ Wo2, const float* __restrict__ bo2,
                             float* __restrict__ out, int N) {
    __shared__ float sWf[256], sWp[256], sWo1[512], sWo2[256];
    __shared__ float sb[64];  // [bf | bp | bo1 | bo2]
    int t = threadIdx.x;
    for (int i = t; i < 256; i += 256) { sWf[i] = Wf[i]; sWp[i] = Wp[i]; sWo2[i] = Wo2[i]; }
    for (int i = t; i < 512; i += 256) sWo1[i] = Wo1[i];
    if (t < 16) { sb[t] = bf[t]; sb[16 + t] = bp[t]; sb[32 + t] = bo1[t]; sb[48 + t] = bo2[t]; }
    __syncthreads();

    int r = blockIdx.x * blockDim.x + t;
    if (r >= N) return;

    float s[16], x[16], y[16], rv[16], z[16], o[16];
    const float4* Sp = (const float4*)(S + (size_t)r * EMB);
    const float4* Rp = (const float4*)(rf + (size_t)r * EMB);
#pragma unroll
    for (int k = 0; k < 4; ++k) {
        float4 v = Sp[k];
        s[4 * k] = v.x; s[4 * k + 1] = v.y; s[4 * k + 2] = v.z; s[4 * k + 3] = v.w;
        float4 w = Rp[k];
        rv[4 * k] = w.x; rv[4 * k + 1] = w.y; rv[4 * k + 2] = w.z; rv[4 * k + 3] = w.w;
    }
    float c = (float)deg[r];

#pragma unroll
    for (int j = 0; j < 16; ++j) {
        float a = c * sb[j];
#pragma unroll
        for (int k = 0; k < 16; ++k) a = fmaf(s[k], sWf[k * 16 + j], a);
        x[j] = fmaxf(a, 0.0f);
    }
#pragma unroll
    for (int j = 0; j < 16; ++j) {
        float a = sb[16 + j];
#pragma unroll
        for (int k = 0; k < 16; ++k) a = fmaf(x[k], sWp[k * 16 + j], a);
        y[j] = a;
    }
#pragma unroll
    for (int j = 0; j < 16; ++j) {
        float a = sb[32 + j];
#pragma unroll
        for (int k = 0; k < 16; ++k) a = fmaf(y[k], sWo1[k * 16 + j], a);
#pragma unroll
        for (int k = 0; k < 16; ++k) a = fmaf(rv[k], sWo1[(16 + k) * 16 + j], a);
        z[j] = fmaxf(a, 0.0f);
    }
#pragma unroll
    for (int j = 0; j < 16; ++j) {
        float a = sb[48 + j];
#pragma unroll
        for (int k = 0; k < 16; ++k) a = fmaf(z[k], sWo2[k * 16 + j], a);
        o[j] = a;
    }
    float4* Op = (float4*)(out + (size_t)r * EMB);
#pragma unroll
    for (int k = 0; k < 4; ++k)
        Op[k] = make_float4(o[4 * k], o[4 * k + 1], o[4 * k + 2], o[4 * k + 3]);
}

extern "C" void kernel_launch(void* const* d_in, const int* in_sizes, int n_in,
                              void* d_out, int out_size, void* d_ws, size_t ws_size,
                              hipStream_t stream) {
    const float* lf     = (const float*)d_in[0];
    const int*   eidx   = (const int*)d_in[1];
    const float* ef     = (const float*)d_in[2];
    const float* rf     = (const float*)d_in[3];
    const float* W_left = (const float*)d_in[4];
    const float* b_left = (const float*)d_in[5];
    const float* W_edge = (const float*)d_in[6];
    const float* W_right= (const float*)d_in[7];
    const float* W_final= (const float*)d_in[8];
    const float* b_final= (const float*)d_in[9];
    const float* W_post = (const float*)d_in[10];
    const float* b_post = (const float*)d_in[11];
    const float* W_out1 = (const float*)d_in[12];
    const float* b_out1 = (const float*)d_in[13];
    const float* W_out2 = (const float*)d_in[14];
    const float* b_out2 = (const float*)d_in[15];

    int n_left  = in_sizes[0] / EMB;
    int E       = in_sizes[2];
    int n_right = in_sizes[3] / EMB;
    float* out = (float*)d_out;

    int NB = (n_right + NRB - 1) / NRB;

    size_t need = (size_t)E * 8
                + ((size_t)n_left + 2 * (size_t)n_right) * EMB * 4
                + (size_t)n_right * 4
                + (size_t)(3 * MAXNB + 1) * 4;

    if (ws_size >= need && NB <= MAXNB) {
        // ---------- bucket-partition path ----------
        u64*   rec   = (u64*)d_ws;
        float* L     = (float*)(rec + (size_t)E);
        float* R     = L + (size_t)n_left * EMB;
        float* S     = R + (size_t)n_right * EMB;
        int*   deg   = (int*)(S + (size_t)n_right * EMB);
        int*   bhist = deg + n_right;
        int*   boff  = bhist + MAXNB;       // NB+1 entries
        int*   gcur  = boff + MAXNB + 1;

        zero_i32<<<(NB + 255) / 256, 256, 0, stream>>>(bhist, NB);
        linear16_kernel<<<(n_left * EMB + 255) / 256, 256, 0, stream>>>(lf, W_left, b_left, L, n_left);
        linear16_kernel<<<(n_right * EMB + 255) / 256, 256, 0, stream>>>(rf, W_right, nullptr, R, n_right);

        bucket_hist_kernel<<<2048, 256, 0, stream>>>(eidx + E, bhist, E, NB);
        bucket_scan_kernel<<<1, 512, 0, stream>>>(bhist, boff, gcur, NB);

        int nchunks = (E + CHUNK - 1) / CHUNK;
        partition_kernel<<<nchunks, 256, 0, stream>>>(eidx, ef, gcur, rec, E, NB);

        bucket_gather_kernel<<<NB, 1024, 0, stream>>>(rec, boff, L, R, W_edge, S, deg, n_right);

        final_kernel<<<(n_right + 255) / 256, 256, 0, stream>>>(S, deg, rf,
            W_final, b_final, W_post, b_post, W_out1, b_out1, W_out2, b_out2, out, n_right);
    } else {
        // ---------- fallback: atomic scatter path ----------
        float* L   = (float*)d_ws;
        float* R   = L + (size_t)n_left * EMB;
        float* S   = R + (size_t)n_right * EMB;
        int*   cnt = (int*)(S + (size_t)n_right * EMB);

        zero_f32<<<2048, 256, 0, stream>>>(S, (size_t)n_right * EMB);
        zero_i32<<<(n_right + 255) / 256, 256, 0, stream>>>(cnt, n_right);

        linear16_kernel<<<(n_left * EMB + 255) / 256, 256, 0, stream>>>(lf, W_left, b_left, L, n_left);
        linear16_kernel<<<(n_right * EMB + 255) / 256, 256, 0, stream>>>(rf, W_right, nullptr, R, n_right);

        long long ethreads = (long long)E * EMB;
        edge_kernel<<<(unsigned)((ethreads + 255) / 256), 256, 0, stream>>>(eidx, ef, L, R, W_edge, S, cnt, E);

        final_kernel<<<(n_right + 255) / 256, 256, 0, stream>>>(S, cnt, rf,
            W_final, b_final, W_post, b_post, W_out1, b_out1, W_out2, b_out2, out, n_right);
    }
}

// Round 4
// 334.579 us; speedup vs baseline: 2.1400x; 1.5594x over previous
//
#include <hip/hip_runtime.h>

#define EMB 16

__global__ void zero_f32(float* __restrict__ p, size_t n) {
    size_t i = (size_t)blockIdx.x * blockDim.x + threadIdx.x;
    size_t stride = (size_t)gridDim.x * blockDim.x;
    for (; i < n; i += stride) p[i] = 0.0f;
}

__global__ void zero_i32(int* __restrict__ p, int n) {
    int i = blockIdx.x * blockDim.x + threadIdx.x;
    if (i < n) p[i] = 0;
}

// Y[row,j] = X[row,:] @ W[:,j] + (b ? b[j] : 0).  One thread per (row, j).
__global__ void linear16_kernel(const float* __restrict__ X, const float* __restrict__ W,
                                const float* __restrict__ b, float* __restrict__ Y, int N) {
    int tid = blockIdx.x * blockDim.x + threadIdx.x;
    int row = tid >> 4;
    int j = tid & 15;
    if (row >= N) return;
    float acc = b ? b[j] : 0.0f;
    const float* xr = X + (size_t)row * EMB;
#pragma unroll
    for (int k = 0; k < EMB; ++k) acc = fmaf(xr[k], W[k * EMB + j], acc);
    Y[(size_t)row * EMB + j] = acc;
}

// One 16-lane group per edge; lane j handles component j.
// S[r,j] += relu(L[l,j] + ef[e]*We[j] + R[r,j]);  cnt[r] += 1 (lane 0).
// unsafeAtomicAdd -> native global_atomic_add_f32 (no CAS loop).
__global__ void edge_kernel(const int* __restrict__ eidx, const float* __restrict__ ef,
                            const float* __restrict__ L, const float* __restrict__ R,
                            const float* __restrict__ We, float* __restrict__ S,
                            int* __restrict__ cnt, int E) {
    long long tid = (long long)blockIdx.x * blockDim.x + threadIdx.x;
    int e = (int)(tid >> 4);
    int j = (int)(tid & 15);
    if (e >= E) return;
    int l = eidx[e];
    int r = eidx[E + e];
    float v = L[(size_t)l * EMB + j] + ef[e] * We[j] + R[(size_t)r * EMB + j];
    v = fmaxf(v, 0.0f);
    unsafeAtomicAdd(&S[(size_t)r * EMB + j], v);
    if (j == 0) atomicAdd(&cnt[r], 1);
}

// ---------------- per-node epilogue ----------------
// agg = S@Wf + deg*bf ; post = relu(agg)@Wp + bp ; h=[post, rf] ;
// out = relu(h@Wo1 + bo1)@Wo2 + bo2.  One thread per node.
__global__ void final_kernel(const float* __restrict__ S, const int* __restrict__ deg,
                             const float* __restrict__ rf,
                             const float* __restrict__ Wf, const float* __restrict__ bf,
                             const float* __restrict__ Wp, const float* __restrict__ bp,
                             const float* __restrict__ Wo1, const float* __restrict__ bo1,
                             const float* __restrict__ Wo2, const float* __restrict__ bo2,
                             float* __restrict__ out, int N) {
    __shared__ float sWf[256], sWp[256], sWo1[512], sWo2[256];
    __shared__ float sb[64];  // [bf | bp | bo1 | bo2]
    int t = threadIdx.x;
    for (int i = t; i < 256; i += 256) { sWf[i] = Wf[i]; sWp[i] = Wp[i]; sWo2[i] = Wo2[i]; }
    for (int i = t; i < 512; i += 256) sWo1[i] = Wo1[i];
    if (t < 16) { sb[t] = bf[t]; sb[16 + t] = bp[t]; sb[32 + t] = bo1[t]; sb[48 + t] = bo2[t]; }
    __syncthreads();

    int r = blockIdx.x * blockDim.x + t;
    if (r >= N) return;

    float s[16], x[16], y[16], rv[16], z[16], o[16];
    const float4* Sp = (const float4*)(S + (size_t)r * EMB);
    const float4* Rp = (const float4*)(rf + (size_t)r * EMB);
#pragma unroll
    for (int k = 0; k < 4; ++k) {
        float4 v = Sp[k];
        s[4 * k] = v.x; s[4 * k + 1] = v.y; s[4 * k + 2] = v.z; s[4 * k + 3] = v.w;
        float4 w = Rp[k];
        rv[4 * k] = w.x; rv[4 * k + 1] = w.y; rv[4 * k + 2] = w.z; rv[4 * k + 3] = w.w;
    }
    float c = (float)deg[r];

#pragma unroll
    for (int j = 0; j < 16; ++j) {
        float a = c * sb[j];
#pragma unroll
        for (int k = 0; k < 16; ++k) a = fmaf(s[k], sWf[k * 16 + j], a);
        x[j] = fmaxf(a, 0.0f);
    }
#pragma unroll
    for (int j = 0; j < 16; ++j) {
        float a = sb[16 + j];
#pragma unroll
        for (int k = 0; k < 16; ++k) a = fmaf(x[k], sWp[k * 16 + j], a);
        y[j] = a;
    }
#pragma unroll
    for (int j = 0; j < 16; ++j) {
        float a = sb[32 + j];
#pragma unroll
        for (int k = 0; k < 16; ++k) a = fmaf(y[k], sWo1[k * 16 + j], a);
#pragma unroll
        for (int k = 0; k < 16; ++k) a = fmaf(rv[k], sWo1[(16 + k) * 16 + j], a);
        z[j] = fmaxf(a, 0.0f);
    }
#pragma unroll
    for (int j = 0; j < 16; ++j) {
        float a = sb[48 + j];
#pragma unroll
        for (int k = 0; k < 16; ++k) a = fmaf(z[k], sWo2[k * 16 + j], a);
        o[j] = a;
    }
    float4* Op = (float4*)(out + (size_t)r * EMB);
#pragma unroll
    for (int k = 0; k < 4; ++k)
        Op[k] = make_float4(o[4 * k], o[4 * k + 1], o[4 * k + 2], o[4 * k + 3]);
}

extern "C" void kernel_launch(void* const* d_in, const int* in_sizes, int n_in,
                              void* d_out, int out_size, void* d_ws, size_t ws_size,
                              hipStream_t stream) {
    const float* lf     = (const float*)d_in[0];
    const int*   eidx   = (const int*)d_in[1];
    const float* ef     = (const float*)d_in[2];
    const float* rf     = (const float*)d_in[3];
    const float* W_left = (const float*)d_in[4];
    const float* b_left = (const float*)d_in[5];
    const float* W_edge = (const float*)d_in[6];
    const float* W_right= (const float*)d_in[7];
    const float* W_final= (const float*)d_in[8];
    const float* b_final= (const float*)d_in[9];
    const float* W_post = (const float*)d_in[10];
    const float* b_post = (const float*)d_in[11];
    const float* W_out1 = (const float*)d_in[12];
    const float* b_out1 = (const float*)d_in[13];
    const float* W_out2 = (const float*)d_in[14];
    const float* b_out2 = (const float*)d_in[15];

    int n_left  = in_sizes[0] / EMB;
    int E       = in_sizes[2];
    int n_right = in_sizes[3] / EMB;
    float* out = (float*)d_out;

    float* L   = (float*)d_ws;
    float* R   = L + (size_t)n_left * EMB;
    float* S   = R + (size_t)n_right * EMB;
    int*   cnt = (int*)(S + (size_t)n_right * EMB);

    zero_f32<<<2048, 256, 0, stream>>>(S, (size_t)n_right * EMB);
    zero_i32<<<(n_right + 255) / 256, 256, 0, stream>>>(cnt, n_right);

    linear16_kernel<<<(n_left * EMB + 255) / 256, 256, 0, stream>>>(lf, W_left, b_left, L, n_left);
    linear16_kernel<<<(n_right * EMB + 255) / 256, 256, 0, stream>>>(rf, W_right, nullptr, R, n_right);

    long long ethreads = (long long)E * EMB;
    edge_kernel<<<(unsigned)((ethreads + 255) / 256), 256, 0, stream>>>(eidx, ef, L, R, W_edge, S, cnt, E);

    final_kernel<<<(n_right + 255) / 256, 256, 0, stream>>>(S, cnt, rf,
        W_final, b_final, W_post, b_post, W_out1, b_out1, W_out2, b_out2, out, n_right);
}